// Round 11
// baseline (241.948 us; speedup 1.0000x reference)
//
#include <hip/hip_runtime.h>

// Problem constants
#define N_TOTAL   65536   // B*H*W = 64*32*32
#define HW_SZ     1024    // H*W
#define CDIM      64      // embedding dim (= C)
#define K_CODES   1024
#define OUT_ELEMS 4194304 // 64*64*32*32
#define QT        256     // queries per block (32 per wave, rt=2, 8 waves)
#define NCHUNK    4       // 4 chunks of 256 codes (64 KB each), double-buffered
#define TAU       0.004f  // rescue margin (> 2x analytic bf16x3 error bound ~1.5e-3)

// ws layout (bytes):
//   0      : enorm[1024]   f32
//   4096   : hist[1024]    u32
//   8192   : partials[256] f32
//   12288  : btab (256 KB) bf16 hi/lo table in MFMA B-FRAGMENT order:
//            short index = ct*2048 + kc*1024 + h*512 + lane*8 + j
//            code = ct*16 + (lane&15), dim = (kc*4 + (lane>>4))*8 + j

typedef __attribute__((ext_vector_type(8))) short short8;
typedef __attribute__((ext_vector_type(4))) float f32x4;

__device__ __forceinline__ unsigned short f2bf(float x) {
    unsigned u = __float_as_uint(x);
    return (unsigned short)((u + 0x7FFFu + ((u >> 16) & 1u)) >> 16);   // RNE
}
__device__ __forceinline__ float bf2f(unsigned short h) {
    return __uint_as_float(((unsigned)h) << 16);
}
__device__ __forceinline__ void gload_lds16(const void* g, void* l) {
    __builtin_amdgcn_global_load_lds(
        (const __attribute__((address_space(1))) void*)g,
        (__attribute__((address_space(3))) void*)l, 16, 0, 0);
}

// keep one 16B short8 alive as 4 dwords (rule #17: prevent DCE without cost)
#define KEEPB(B) asm volatile("" :: \
    "v"(((const int*)&(B))[0]), "v"(((const int*)&(B))[1]), \
    "v"(((const int*)&(B))[2]), "v"(((const int*)&(B))[3]))

// ---------------------------------------------------------------- k_prep ----
__global__ void k_prep(const float* __restrict__ emb, float* __restrict__ enorm,
                       short* __restrict__ btab, unsigned int* __restrict__ hist) {
    int gid = blockIdx.x * 256 + threadIdx.x;        // 0..16383
    int r  = gid >> 4;           // code 0..1023
    int d0 = (gid & 15) * 4;     // dim base 0..60
    float4 v = *(const float4*)(emb + gid * 4);
    float s = v.x * v.x + v.y * v.y + v.z * v.z + v.w * v.w;
#pragma unroll
    for (int off = 1; off < 16; off <<= 1) s += __shfl_xor(s, off, 64);
    if ((gid & 15) == 0) enorm[r] = s;

    float vv[4] = {v.x, v.y, v.z, v.w};
    short h[4], l[4];
#pragma unroll
    for (int j = 0; j < 4; ++j) {
        unsigned short hh = f2bf(vv[j]);
        h[j] = (short)hh;
        l[j] = (short)f2bf(vv[j] - bf2f(hh));
    }
    int base = (r >> 4) * 2048 + (d0 >> 5) * 1024
             + ((((d0 >> 3) & 3) * 16 + (r & 15)) * 8) + (d0 & 7);
    *(short4*)&btab[base]       = make_short4(h[0], h[1], h[2], h[3]);
    *(short4*)&btab[base + 512] = make_short4(l[0], l[1], l[2], l[3]);

    if (gid < K_CODES) hist[gid] = 0u;
}

// -------------------------------------------------------------- k_argmin ----
// Session-best pipeline restored verbatim (round 5): 512 thr = 8 waves,
// QT=256 (2 query-tiles/wave), LDS-resident 4x256-code double-buffered
// chunks, explicit Ba/Bb register pipeline, bf16x3, top-2 + TAU rescue,
// fused epilogue with hist atomics + bf16 table gather out-write.
__global__ __launch_bounds__(512, 2)
void k_argmin(const float* __restrict__ x, const float* __restrict__ emb,
              const short* __restrict__ btab, const float* __restrict__ enorm,
              unsigned int* __restrict__ hist, float* __restrict__ partials,
              float* __restrict__ out) {
    __shared__ __align__(16) short bufs[2][16 * 2048];   // 2 x 64 KB chunk buffers
    __shared__ __align__(16) float ens[K_CODES];         // 4 KB exact fp32 ||e||^2
    __shared__ float xnorm[QT];
    __shared__ float rd1[QT];
    __shared__ float rd2[QT];
    __shared__ int   ri[QT];
    __shared__ int   flist[QT];
    __shared__ __align__(16) float xqf[CDIM];
    __shared__ float wdd[8];
    __shared__ int   wii[8];
    __shared__ float spw[4];
    __shared__ int   nflag;
    float* tile = (float*)bufs;      // 64*72 f32 epilogue transpose, aliases bufs

    const int tid  = threadIdx.x;
    const int lane = tid & 63;
    const int w    = tid >> 6;       // 0..7
    const int quad = lane >> 4;
    const int col  = lane & 15;

    const int n0  = blockIdx.x * QT;
    const int b   = n0 >> 10;
    const int hw0 = n0 & 1023;        // 256-aligned

    auto stage_async = [&](int c, int bsel) {
        const short* src = btab + c * (16 * 2048);
#pragma unroll
        for (int i = 0; i < 8; ++i) {
            int idx = i * 512 + tid;                  // 16B units, 0..4095
            gload_lds16(&src[idx * 8], (void*)&bufs[bsel][idx * 8]);
        }
    };

    stage_async(0, 0);
    if (tid < 256) gload_lds16(&enorm[tid * 4], (void*)&ens[tid * 4]);

    const float* xb = x + b * (CDIM * HW_SZ) + hw0 + col;
    short8 afr[2][2][2];     // [rt][kc][hi/lo]
#pragma unroll
    for (int rt = 0; rt < 2; ++rt) {
        float nloc = 0.f;
#pragma unroll
        for (int kc = 0; kc < 2; ++kc) {
#pragma unroll
            for (int j = 0; j < 8; ++j) {
                int c0 = (kc * 4 + quad) * 8 + j;
                float v = xb[c0 * HW_SZ + w * 32 + rt * 16];
                unsigned short hh = f2bf(v);
                afr[rt][kc][0][j] = (short)hh;
                afr[rt][kc][1][j] = (short)f2bf(v - bf2f(hh));
                nloc = __builtin_fmaf(v, v, nloc);
            }
        }
        nloc += __shfl_xor(nloc, 16, 64);
        nloc += __shfl_xor(nloc, 32, 64);
        if (quad == 0) xnorm[w * 32 + rt * 16 + col] = nloc;
    }

    float d1[8], d2[8];
    int   i1[8];
#pragma unroll
    for (int t = 0; t < 8; ++t) { d1[t] = 3.4e38f; d2[t] = 3.4e38f; i1[t] = 0; }

    __syncthreads();   // chunk 0 + ens + xnorm ready

    for (int c = 0; c < NCHUNK; ++c) {
        if (c + 1 < NCHUNK) stage_async(c + 1, (c + 1) & 1);
        const short* bs = &bufs[c & 1][0];
        const int cbase = c * 256;

        short8 Ba[4], Bb[4];          // [kc0hi, kc0lo, kc1hi, kc1lo]
        float  ena, enb;
        auto LDB = [&](short8 (&B)[4], float& en, int ctl) {
            const short* fp = bs + ctl * 2048 + lane * 8;
            B[0] = *(const short8*)(fp);
            B[1] = *(const short8*)(fp + 512);
            B[2] = *(const short8*)(fp + 1024);
            B[3] = *(const short8*)(fp + 1536);
            en   = ens[cbase + ctl * 16 + col];
        };
        auto COMP = [&](const short8 (&B)[4], float en, int mycode) {
#pragma unroll
            for (int rt = 0; rt < 2; ++rt) {
                f32x4 a0 = {0.f, 0.f, 0.f, 0.f};
                f32x4 a1 = {0.f, 0.f, 0.f, 0.f};
                a0 = __builtin_amdgcn_mfma_f32_16x16x32_bf16(afr[rt][0][1], B[0], a0, 0, 0, 0);
                a1 = __builtin_amdgcn_mfma_f32_16x16x32_bf16(afr[rt][1][1], B[2], a1, 0, 0, 0);
                a0 = __builtin_amdgcn_mfma_f32_16x16x32_bf16(afr[rt][0][0], B[1], a0, 0, 0, 0);
                a1 = __builtin_amdgcn_mfma_f32_16x16x32_bf16(afr[rt][1][0], B[3], a1, 0, 0, 0);
                a0 = __builtin_amdgcn_mfma_f32_16x16x32_bf16(afr[rt][0][0], B[0], a0, 0, 0, 0);
                a1 = __builtin_amdgcn_mfma_f32_16x16x32_bf16(afr[rt][1][0], B[2], a1, 0, 0, 0);
#pragma unroll
                for (int reg = 0; reg < 4; ++reg) {
                    int t = rt * 4 + reg;
                    float dot = a0[reg] + a1[reg];
                    float d   = __builtin_fmaf(dot, -2.f, en);
                    float d1o = d1[t];
                    d2[t] = __builtin_amdgcn_fmed3f(d, d1o, d2[t]);
                    d1[t] = fminf(d, d1o);
                    i1[t] = (d < d1o) ? mycode : i1[t];
                }
            }
        };

        LDB(Ba, ena, 0);
#pragma unroll
        for (int ctl = 0; ctl < 16; ctl += 2) {
            LDB(Bb, enb, ctl + 1);
            COMP(Ba, ena, cbase + ctl * 16 + col);
            if (ctl + 2 < 16) LDB(Ba, ena, ctl + 2);
            COMP(Bb, enb, cbase + (ctl + 1) * 16 + col);
        }
        __syncthreads();
    }

    // reduce across 16 cols per query row (codes ascend with col: lex-min ok)
#pragma unroll
    for (int t = 0; t < 8; ++t) {
        float a1 = d1[t], a2 = d2[t];
        int ai = i1[t];
#pragma unroll
        for (int off = 1; off < 16; off <<= 1) {
            float o1 = __shfl_xor(a1, off, 64);
            float o2 = __shfl_xor(a2, off, 64);
            int   oi = __shfl_xor(ai, off, 64);
            if (o1 < a1 || (o1 == a1 && oi < ai)) {
                float loser = a1; a2 = fminf(fminf(a2, o2), loser); a1 = o1; ai = oi;
            } else {
                a2 = fminf(fminf(a2, o2), o1);
            }
        }
        d1[t] = a1; d2[t] = a2; i1[t] = ai;
    }

    if (tid == 0) nflag = 0;
    if (col == 0) {
#pragma unroll
        for (int rt = 0; rt < 2; ++rt)
#pragma unroll
            for (int reg = 0; reg < 4; ++reg) {
                int t = rt * 4 + reg;
                int m = w * 32 + rt * 16 + quad * 4 + reg;
                rd1[m] = d1[t];
                rd2[m] = d2[t];
                ri [m] = i1[t];
            }
    }
    __syncthreads();

    if (tid < QT) {
        if (rd2[tid] - rd1[tid] < TAU) {
            int slot = atomicAdd(&nflag, 1);
            flist[slot] = tid;
        }
    }
    __syncthreads();

    // ---- in-block exact fp32 rescue (avg nflag ~1 per block) ----
    for (int f = 0; f < nflag; ++f) {
        const int q = flist[f];
        if (tid < CDIM) xqf[tid] = x[b * (CDIM * HW_SZ) + tid * HW_SZ + hw0 + q];
        __syncthreads();
        float dm = 3.4e38f; int im = 0;
#pragma unroll
        for (int cd = 0; cd < 2; ++cd) {
            const int k = tid + cd * 512;            // codes ascend with cd
            const float4* er = (const float4*)(emb + k * CDIM);
            const float4* xr = (const float4*)xqf;
            float dot = 0.f;
#pragma unroll
            for (int c4 = 0; c4 < 16; ++c4) {
                float4 e = er[c4], xv = xr[c4];
                dot += e.x * xv.x + e.y * xv.y + e.z * xv.z + e.w * xv.w;
            }
            float d = ens[k] - 2.f * dot;            // exact fp32
            if (d < dm) { dm = d; im = k; }
        }
#pragma unroll
        for (int off = 1; off < 64; off <<= 1) {
            float od = __shfl_xor(dm, off, 64);
            int   oi = __shfl_xor(im, off, 64);
            if (od < dm || (od == dm && oi < im)) { dm = od; im = oi; }
        }
        if (lane == 0) { wdd[w] = dm; wii[w] = im; }
        __syncthreads();
        if (tid == 0) {
            float bd = wdd[0]; int bi = wii[0];
#pragma unroll
            for (int ww = 1; ww < 8; ++ww)
                if (wdd[ww] < bd || (wdd[ww] == bd && wii[ww] < bi)) { bd = wdd[ww]; bi = wii[ww]; }
            rd1[q] = bd; ri[q] = bi;                 // final exact result
        }
        __syncthreads();
    }

    // ---- epilogue on FINAL indices: hist, SSE partial ----
    if (tid < QT) {
        int ai = ri[tid];
        atomicAdd(&hist[ai], 1u);
        float sp = rd1[tid] + xnorm[tid];            // ||q-x||^2 (exact for rescued)
#pragma unroll
        for (int off = 32; off; off >>= 1) sp += __shfl_down(sp, off, 64);
        if (lane == 0) spw[tid >> 6] = sp;
    }
    __syncthreads();
    if (tid == 0) partials[blockIdx.x] = spw[0] + spw[1] + spw[2] + spw[3];

    // ---- fused output write: four 64-query quarters through the LDS tile ----
#pragma unroll
    for (int h = 0; h < 4; ++h) {
        {   // gather from frag-layout table: thread = (q = tid>>3, j8 = tid&7)
            int q = tid >> 3, j8 = tid & 7;          // 8 dims per thread
            int code = ri[h * 64 + q];
            int ct = code >> 4, cl = code & 15;
            int kc = j8 >> 2, qd = j8 & 3;
            const short* tb = btab + ct * 2048 + kc * 1024;
            short8 hi = *(const short8*)&tb[(qd * 16 + cl) * 8];
            short8 lo = *(const short8*)&tb[512 + (qd * 16 + cl) * 8];
            float* dst = &tile[q * 72 + j8 * 8];
#pragma unroll
            for (int k = 0; k < 8; ++k)
                dst[k] = bf2f((unsigned short)hi[k]) + bf2f((unsigned short)lo[k]);
        }
        __syncthreads();
        {   // transposed coalesced write
            int c = tid >> 3;
            float* ob = out + b * (CDIM * HW_SZ) + c * HW_SZ + hw0 + h * 64;
#pragma unroll
            for (int p = 0; p < 2; ++p) {
                int q = ((tid & 7) + p * 8) * 4;   // 0..60
                float4 v;
                v.x = tile[(q + 0) * 72 + c];
                v.y = tile[(q + 1) * 72 + c];
                v.z = tile[(q + 2) * 72 + c];
                v.w = tile[(q + 3) * 72 + c];
                *(float4*)&ob[q] = v;
            }
        }
        if (h < 3) __syncthreads();
    }
}

// ------------------------------------------------------------- k_abl_full ---
// ABLATION ARM 1: K-loop only, 4 passes over the whole table (16 chunks).
// No epilogue, no global writes; results kept alive via asm. Appears in
// rocprof top-5 -> precise 4x K-loop timing.
__global__ __launch_bounds__(512, 2)
void k_abl_full(const float* __restrict__ x, const short* __restrict__ btab,
                const float* __restrict__ enorm) {
    __shared__ __align__(16) short bufs[2][16 * 2048];
    __shared__ __align__(16) float ens[K_CODES];
    __shared__ float xnorm[QT];

    const int tid  = threadIdx.x;
    const int lane = tid & 63;
    const int w    = tid >> 6;
    const int quad = lane >> 4;
    const int col  = lane & 15;

    const int n0  = blockIdx.x * QT;
    const int b   = n0 >> 10;
    const int hw0 = n0 & 1023;

    auto stage_async = [&](int c, int bsel) {
        const short* src = btab + c * (16 * 2048);
#pragma unroll
        for (int i = 0; i < 8; ++i) {
            int idx = i * 512 + tid;
            gload_lds16(&src[idx * 8], (void*)&bufs[bsel][idx * 8]);
        }
    };

    stage_async(0, 0);
    if (tid < 256) gload_lds16(&enorm[tid * 4], (void*)&ens[tid * 4]);

    const float* xb = x + b * (CDIM * HW_SZ) + hw0 + col;
    short8 afr[2][2][2];
#pragma unroll
    for (int rt = 0; rt < 2; ++rt) {
        float nloc = 0.f;
#pragma unroll
        for (int kc = 0; kc < 2; ++kc) {
#pragma unroll
            for (int j = 0; j < 8; ++j) {
                int c0 = (kc * 4 + quad) * 8 + j;
                float v = xb[c0 * HW_SZ + w * 32 + rt * 16];
                unsigned short hh = f2bf(v);
                afr[rt][kc][0][j] = (short)hh;
                afr[rt][kc][1][j] = (short)f2bf(v - bf2f(hh));
                nloc = __builtin_fmaf(v, v, nloc);
            }
        }
        if (quad == 0) xnorm[w * 32 + rt * 16 + col] = nloc;
    }

    float d1[8], d2[8];
    int   i1[8];
#pragma unroll
    for (int t = 0; t < 8; ++t) { d1[t] = 3.4e38f; d2[t] = 3.4e38f; i1[t] = 0; }

    __syncthreads();

    for (int g = 0; g < 4 * NCHUNK; ++g) {           // 4 amplification passes
        if (g + 1 < 4 * NCHUNK) stage_async((g + 1) & 3, (g + 1) & 1);
        const short* bs = &bufs[g & 1][0];
        const int cbase = (g & 3) * 256;

        short8 Ba[4], Bb[4];
        float  ena, enb;
        auto LDB = [&](short8 (&B)[4], float& en, int ctl) {
            const short* fp = bs + ctl * 2048 + lane * 8;
            B[0] = *(const short8*)(fp);
            B[1] = *(const short8*)(fp + 512);
            B[2] = *(const short8*)(fp + 1024);
            B[3] = *(const short8*)(fp + 1536);
            en   = ens[cbase + ctl * 16 + col];
        };
        auto COMP = [&](const short8 (&B)[4], float en, int mycode) {
#pragma unroll
            for (int rt = 0; rt < 2; ++rt) {
                f32x4 a0 = {0.f, 0.f, 0.f, 0.f};
                f32x4 a1 = {0.f, 0.f, 0.f, 0.f};
                a0 = __builtin_amdgcn_mfma_f32_16x16x32_bf16(afr[rt][0][1], B[0], a0, 0, 0, 0);
                a1 = __builtin_amdgcn_mfma_f32_16x16x32_bf16(afr[rt][1][1], B[2], a1, 0, 0, 0);
                a0 = __builtin_amdgcn_mfma_f32_16x16x32_bf16(afr[rt][0][0], B[1], a0, 0, 0, 0);
                a1 = __builtin_amdgcn_mfma_f32_16x16x32_bf16(afr[rt][1][0], B[3], a1, 0, 0, 0);
                a0 = __builtin_amdgcn_mfma_f32_16x16x32_bf16(afr[rt][0][0], B[0], a0, 0, 0, 0);
                a1 = __builtin_amdgcn_mfma_f32_16x16x32_bf16(afr[rt][1][0], B[2], a1, 0, 0, 0);
#pragma unroll
                for (int reg = 0; reg < 4; ++reg) {
                    int t = rt * 4 + reg;
                    float dot = a0[reg] + a1[reg];
                    float d   = __builtin_fmaf(dot, -2.f, en);
                    float d1o = d1[t];
                    d2[t] = __builtin_amdgcn_fmed3f(d, d1o, d2[t]);
                    d1[t] = fminf(d, d1o);
                    i1[t] = (d < d1o) ? mycode : i1[t];
                }
            }
        };

        LDB(Ba, ena, 0);
#pragma unroll
        for (int ctl = 0; ctl < 16; ctl += 2) {
            LDB(Bb, enb, ctl + 1);
            COMP(Ba, ena, cbase + ctl * 16 + col);
            if (ctl + 2 < 16) LDB(Ba, ena, ctl + 2);
            COMP(Bb, enb, cbase + (ctl + 1) * 16 + col);
        }
        __syncthreads();
    }

#pragma unroll
    for (int t = 0; t < 8; ++t)
        asm volatile("" :: "v"(d1[t]), "v"(d2[t]), "v"(i1[t]));
}

// ----------------------------------------------------------- k_abl_nocomp ---
// ABLATION ARM 2: identical memory machinery (stage + barriers + LDB ds_reads)
// with MFMA + min-update DELETED. B/en kept alive dword-wise. Timing recovered
// from dur arithmetic: T_nocomp ~ dur - 124 - T_full.
__global__ __launch_bounds__(512, 2)
void k_abl_nocomp(const float* __restrict__ x, const short* __restrict__ btab,
                  const float* __restrict__ enorm) {
    __shared__ __align__(16) short bufs[2][16 * 2048];
    __shared__ __align__(16) float ens[K_CODES];
    __shared__ float xnorm[QT];

    const int tid  = threadIdx.x;
    const int lane = tid & 63;
    const int w    = tid >> 6;
    const int quad = lane >> 4;
    const int col  = lane & 15;

    const int n0  = blockIdx.x * QT;
    const int b   = n0 >> 10;
    const int hw0 = n0 & 1023;

    auto stage_async = [&](int c, int bsel) {
        const short* src = btab + c * (16 * 2048);
#pragma unroll
        for (int i = 0; i < 8; ++i) {
            int idx = i * 512 + tid;
            gload_lds16(&src[idx * 8], (void*)&bufs[bsel][idx * 8]);
        }
    };

    stage_async(0, 0);
    if (tid < 256) gload_lds16(&enorm[tid * 4], (void*)&ens[tid * 4]);

    const float* xb = x + b * (CDIM * HW_SZ) + hw0 + col;
    short8 afr[2][2][2];
#pragma unroll
    for (int rt = 0; rt < 2; ++rt) {
        float nloc = 0.f;
#pragma unroll
        for (int kc = 0; kc < 2; ++kc) {
#pragma unroll
            for (int j = 0; j < 8; ++j) {
                int c0 = (kc * 4 + quad) * 8 + j;
                float v = xb[c0 * HW_SZ + w * 32 + rt * 16];
                unsigned short hh = f2bf(v);
                afr[rt][kc][0][j] = (short)hh;
                afr[rt][kc][1][j] = (short)f2bf(v - bf2f(hh));
                nloc = __builtin_fmaf(v, v, nloc);
            }
        }
        if (quad == 0) xnorm[w * 32 + rt * 16 + col] = nloc;
    }
    // keep A fragments alive so the prologue matches arm 1
#pragma unroll
    for (int rt = 0; rt < 2; ++rt)
#pragma unroll
        for (int kc = 0; kc < 2; ++kc) {
            KEEPB(afr[rt][kc][0]); KEEPB(afr[rt][kc][1]);
        }

    __syncthreads();

    for (int g = 0; g < 4 * NCHUNK; ++g) {           // 4 amplification passes
        if (g + 1 < 4 * NCHUNK) stage_async((g + 1) & 3, (g + 1) & 1);
        const short* bs = &bufs[g & 1][0];
        const int cbase = (g & 3) * 256;

        short8 Ba[4], Bb[4];
        float  ena, enb;
        auto LDB = [&](short8 (&B)[4], float& en, int ctl) {
            const short* fp = bs + ctl * 2048 + lane * 8;
            B[0] = *(const short8*)(fp);
            B[1] = *(const short8*)(fp + 512);
            B[2] = *(const short8*)(fp + 1024);
            B[3] = *(const short8*)(fp + 1536);
            en   = ens[cbase + ctl * 16 + col];
        };
        auto KEEP = [&](const short8 (&B)[4], float en) {
            KEEPB(B[0]); KEEPB(B[1]); KEEPB(B[2]); KEEPB(B[3]);
            asm volatile("" :: "v"(en));
        };

        LDB(Ba, ena, 0);
#pragma unroll
        for (int ctl = 0; ctl < 16; ctl += 2) {
            LDB(Bb, enb, ctl + 1);
            KEEP(Ba, ena);
            if (ctl + 2 < 16) LDB(Ba, ena, ctl + 2);
            KEEP(Bb, enb);
        }
        __syncthreads();
    }
}

// --------------------------------------------------------------- k_final ----
__global__ void k_final(const float* __restrict__ partials,
                        const unsigned int* __restrict__ hist,
                        float* __restrict__ out) {
    int tid = threadIdx.x;   // 256
    float ss = partials[tid];
    float s = 0.f;
#pragma unroll
    for (int i = 0; i < 4; ++i) {
        float p = (float)hist[i * 256 + tid] * (1.0f / 65536.0f);
        s += p * logf(p + 1e-10f);
    }
    __shared__ float fin[8];
#pragma unroll
    for (int off = 32; off; off >>= 1) {
        ss += __shfl_down(ss, off, 64);
        s  += __shfl_down(s, off, 64);
    }
    if ((tid & 63) == 0) { fin[tid >> 6] = ss; fin[4 + (tid >> 6)] = s; }
    __syncthreads();
    if (tid == 0) {
        float sse = fin[0] + fin[1] + fin[2] + fin[3];
        float ent = fin[4] + fin[5] + fin[6] + fin[7];
        out[OUT_ELEMS]     = 1.25f * sse * (1.0f / (float)OUT_ELEMS);  // loss
        out[OUT_ELEMS + 1] = expf(-ent);                                // perplexity
    }
}

// ---------------------------------------------------------------- launch ----
extern "C" void kernel_launch(void* const* d_in, const int* in_sizes, int n_in,
                              void* d_out, int out_size, void* d_ws, size_t ws_size,
                              hipStream_t stream) {
    const float* x   = (const float*)d_in[0];
    const float* emb = (const float*)d_in[1];
    float* out = (float*)d_out;
    char* ws = (char*)d_ws;
    float*        enorm    = (float*)(ws);
    unsigned int* hist     = (unsigned int*)(ws + 4096);
    float*        partials = (float*)(ws + 8192);
    short*        btab     = (short*)(ws + 12288);

    k_prep  <<<64, 256, 0, stream>>>(emb, enorm, btab, hist);
    k_argmin<<<N_TOTAL / QT, 512, 0, stream>>>(x, emb, btab, enorm, hist, partials, out);
    k_final <<<1, 256, 0, stream>>>(partials, hist, out);
    // ---- ablation arms (diagnostic, no output effect) ----
    k_abl_full  <<<N_TOTAL / QT, 512, 0, stream>>>(x, btab, enorm);
    k_abl_nocomp<<<N_TOTAL / QT, 512, 0, stream>>>(x, btab, enorm);
}

// Round 12
// 127.250 us; speedup vs baseline: 1.9014x; 1.9014x over previous
//
#include <hip/hip_runtime.h>

// Problem constants
#define N_TOTAL   65536   // B*H*W = 64*32*32
#define HW_SZ     1024    // H*W
#define CDIM      64      // embedding dim (= C)
#define K_CODES   1024
#define OUT_ELEMS 4194304 // 64*64*32*32
#define QT        256     // queries per block (32 per wave, rt=2, 8 waves)
#define NCHUNK    4       // 4 chunks of 256 codes (64 KB each), double-buffered
#define NBLK      (N_TOTAL / QT)   // 256 argmin blocks
#define TAU       0.004f  // rescue margin (> 2x analytic bf16x3 error bound ~1.5e-3)

// ws layout (bytes):
//   0      : enorm[1024]   f32
//   8192   : partials[256] f32
//   12288  : btab (256 KB) bf16 hi/lo table in MFMA B-FRAGMENT order:
//            short index = ct*2048 + kc*1024 + h*512 + lane*8 + j
//            code = ct*16 + (lane&15), dim = (kc*4 + (lane>>4))*8 + j
//   274432 : hbuf[256][512] u32 (512 KB) per-block u16x2-packed histograms
//            (NO global atomics anywhere)

typedef __attribute__((ext_vector_type(8))) short short8;
typedef __attribute__((ext_vector_type(4))) float f32x4;

__device__ __forceinline__ unsigned short f2bf(float x) {
    unsigned u = __float_as_uint(x);
    return (unsigned short)((u + 0x7FFFu + ((u >> 16) & 1u)) >> 16);   // RNE
}
__device__ __forceinline__ float bf2f(unsigned short h) {
    return __uint_as_float(((unsigned)h) << 16);
}
__device__ __forceinline__ void gload_lds16(const void* g, void* l) {
    __builtin_amdgcn_global_load_lds(
        (const __attribute__((address_space(1))) void*)g,
        (__attribute__((address_space(3))) void*)l, 16, 0, 0);
}

// ---------------------------------------------------------------- k_prep ----
__global__ void k_prep(const float* __restrict__ emb, float* __restrict__ enorm,
                       short* __restrict__ btab) {
    int gid = blockIdx.x * 256 + threadIdx.x;        // 0..16383
    int r  = gid >> 4;           // code 0..1023
    int d0 = (gid & 15) * 4;     // dim base 0..60
    float4 v = *(const float4*)(emb + gid * 4);
    float s = v.x * v.x + v.y * v.y + v.z * v.z + v.w * v.w;
#pragma unroll
    for (int off = 1; off < 16; off <<= 1) s += __shfl_xor(s, off, 64);
    if ((gid & 15) == 0) enorm[r] = s;

    float vv[4] = {v.x, v.y, v.z, v.w};
    short h[4], l[4];
#pragma unroll
    for (int j = 0; j < 4; ++j) {
        unsigned short hh = f2bf(vv[j]);
        h[j] = (short)hh;
        l[j] = (short)f2bf(vv[j] - bf2f(hh));
    }
    int base = (r >> 4) * 2048 + (d0 >> 5) * 1024
             + ((((d0 >> 3) & 3) * 16 + (r & 15)) * 8) + (d0 & 7);
    *(short4*)&btab[base]       = make_short4(h[0], h[1], h[2], h[3]);
    *(short4*)&btab[base + 512] = make_short4(l[0], l[1], l[2], l[3]);
}

// -------------------------------------------------------------- k_argmin ----
// K-loop byte-identical to the proven round-5 core (512 thr = 8 waves,
// QT=256, LDS-resident 4x256-code double-buffered chunks, Ba/Bb register
// pipeline, bf16x3, top-2 + TAU rescue). Epilogue changed ONLY in the
// histogram: per-block LDS hist -> one coalesced 2 KB u16x2 row write
// (hbuf[blockIdx]); zero device-scope atomics.
__global__ __launch_bounds__(512, 2)
void k_argmin(const float* __restrict__ x, const float* __restrict__ emb,
              const short* __restrict__ btab, const float* __restrict__ enorm,
              unsigned int* __restrict__ hbuf, float* __restrict__ partials,
              float* __restrict__ out) {
    __shared__ __align__(16) short bufs[2][16 * 2048];   // 2 x 64 KB chunk buffers
    __shared__ __align__(16) float ens[K_CODES];         // 4 KB exact fp32 ||e||^2
    __shared__ float xnorm[QT];
    __shared__ float rd1[QT];
    __shared__ float rd2[QT];
    __shared__ int   ri[QT];
    __shared__ int   flist[QT];
    __shared__ __align__(16) float xqf[CDIM];
    __shared__ float wdd[8];
    __shared__ int   wii[8];
    __shared__ float spw[4];
    __shared__ int   nflag;
    float* tile = (float*)bufs;                          // 64*72 f32, aliases bufs
    unsigned int* lhist = (unsigned int*)((char*)bufs + 32768);  // 4 KB, past tile

    const int tid  = threadIdx.x;
    const int lane = tid & 63;
    const int w    = tid >> 6;       // 0..7
    const int quad = lane >> 4;
    const int col  = lane & 15;

    const int n0  = blockIdx.x * QT;
    const int b   = n0 >> 10;
    const int hw0 = n0 & 1023;        // 256-aligned

    auto stage_async = [&](int c, int bsel) {
        const short* src = btab + c * (16 * 2048);
#pragma unroll
        for (int i = 0; i < 8; ++i) {
            int idx = i * 512 + tid;                  // 16B units, 0..4095
            gload_lds16(&src[idx * 8], (void*)&bufs[bsel][idx * 8]);
        }
    };

    stage_async(0, 0);
    if (tid < 256) gload_lds16(&enorm[tid * 4], (void*)&ens[tid * 4]);

    const float* xb = x + b * (CDIM * HW_SZ) + hw0 + col;
    short8 afr[2][2][2];     // [rt][kc][hi/lo]
#pragma unroll
    for (int rt = 0; rt < 2; ++rt) {
        float nloc = 0.f;
#pragma unroll
        for (int kc = 0; kc < 2; ++kc) {
#pragma unroll
            for (int j = 0; j < 8; ++j) {
                int c0 = (kc * 4 + quad) * 8 + j;
                float v = xb[c0 * HW_SZ + w * 32 + rt * 16];
                unsigned short hh = f2bf(v);
                afr[rt][kc][0][j] = (short)hh;
                afr[rt][kc][1][j] = (short)f2bf(v - bf2f(hh));
                nloc = __builtin_fmaf(v, v, nloc);
            }
        }
        nloc += __shfl_xor(nloc, 16, 64);
        nloc += __shfl_xor(nloc, 32, 64);
        if (quad == 0) xnorm[w * 32 + rt * 16 + col] = nloc;
    }

    float d1[8], d2[8];
    int   i1[8];
#pragma unroll
    for (int t = 0; t < 8; ++t) { d1[t] = 3.4e38f; d2[t] = 3.4e38f; i1[t] = 0; }

    __syncthreads();   // chunk 0 + ens + xnorm ready

    for (int c = 0; c < NCHUNK; ++c) {
        if (c + 1 < NCHUNK) stage_async(c + 1, (c + 1) & 1);
        const short* bs = &bufs[c & 1][0];
        const int cbase = c * 256;

        short8 Ba[4], Bb[4];          // [kc0hi, kc0lo, kc1hi, kc1lo]
        float  ena, enb;
        auto LDB = [&](short8 (&B)[4], float& en, int ctl) {
            const short* fp = bs + ctl * 2048 + lane * 8;
            B[0] = *(const short8*)(fp);
            B[1] = *(const short8*)(fp + 512);
            B[2] = *(const short8*)(fp + 1024);
            B[3] = *(const short8*)(fp + 1536);
            en   = ens[cbase + ctl * 16 + col];
        };
        auto COMP = [&](const short8 (&B)[4], float en, int mycode) {
#pragma unroll
            for (int rt = 0; rt < 2; ++rt) {
                f32x4 a0 = {0.f, 0.f, 0.f, 0.f};
                f32x4 a1 = {0.f, 0.f, 0.f, 0.f};
                a0 = __builtin_amdgcn_mfma_f32_16x16x32_bf16(afr[rt][0][1], B[0], a0, 0, 0, 0);
                a1 = __builtin_amdgcn_mfma_f32_16x16x32_bf16(afr[rt][1][1], B[2], a1, 0, 0, 0);
                a0 = __builtin_amdgcn_mfma_f32_16x16x32_bf16(afr[rt][0][0], B[1], a0, 0, 0, 0);
                a1 = __builtin_amdgcn_mfma_f32_16x16x32_bf16(afr[rt][1][0], B[3], a1, 0, 0, 0);
                a0 = __builtin_amdgcn_mfma_f32_16x16x32_bf16(afr[rt][0][0], B[0], a0, 0, 0, 0);
                a1 = __builtin_amdgcn_mfma_f32_16x16x32_bf16(afr[rt][1][0], B[2], a1, 0, 0, 0);
#pragma unroll
                for (int reg = 0; reg < 4; ++reg) {
                    int t = rt * 4 + reg;
                    float dot = a0[reg] + a1[reg];
                    float d   = __builtin_fmaf(dot, -2.f, en);
                    float d1o = d1[t];
                    d2[t] = __builtin_amdgcn_fmed3f(d, d1o, d2[t]);
                    d1[t] = fminf(d, d1o);
                    i1[t] = (d < d1o) ? mycode : i1[t];
                }
            }
        };

        LDB(Ba, ena, 0);
#pragma unroll
        for (int ctl = 0; ctl < 16; ctl += 2) {
            LDB(Bb, enb, ctl + 1);
            COMP(Ba, ena, cbase + ctl * 16 + col);
            if (ctl + 2 < 16) LDB(Ba, ena, ctl + 2);
            COMP(Bb, enb, cbase + (ctl + 1) * 16 + col);
        }
        __syncthreads();
    }

    // reduce across 16 cols per query row (codes ascend with col: lex-min ok)
#pragma unroll
    for (int t = 0; t < 8; ++t) {
        float a1 = d1[t], a2 = d2[t];
        int ai = i1[t];
#pragma unroll
        for (int off = 1; off < 16; off <<= 1) {
            float o1 = __shfl_xor(a1, off, 64);
            float o2 = __shfl_xor(a2, off, 64);
            int   oi = __shfl_xor(ai, off, 64);
            if (o1 < a1 || (o1 == a1 && oi < ai)) {
                float loser = a1; a2 = fminf(fminf(a2, o2), loser); a1 = o1; ai = oi;
            } else {
                a2 = fminf(fminf(a2, o2), o1);
            }
        }
        d1[t] = a1; d2[t] = a2; i1[t] = ai;
    }

    if (tid == 0) nflag = 0;
    if (col == 0) {
#pragma unroll
        for (int rt = 0; rt < 2; ++rt)
#pragma unroll
            for (int reg = 0; reg < 4; ++reg) {
                int t = rt * 4 + reg;
                int m = w * 32 + rt * 16 + quad * 4 + reg;
                rd1[m] = d1[t];
                rd2[m] = d2[t];
                ri [m] = i1[t];
            }
    }
    __syncthreads();

    if (tid < QT) {
        if (rd2[tid] - rd1[tid] < TAU) {
            int slot = atomicAdd(&nflag, 1);
            flist[slot] = tid;
        }
    }
    __syncthreads();

    // ---- in-block exact fp32 rescue (avg nflag ~1 per block) ----
    for (int f = 0; f < nflag; ++f) {
        const int q = flist[f];
        if (tid < CDIM) xqf[tid] = x[b * (CDIM * HW_SZ) + tid * HW_SZ + hw0 + q];
        __syncthreads();
        float dm = 3.4e38f; int im = 0;
#pragma unroll
        for (int cd = 0; cd < 2; ++cd) {
            const int k = tid + cd * 512;            // codes ascend with cd
            const float4* er = (const float4*)(emb + k * CDIM);
            const float4* xr = (const float4*)xqf;
            float dot = 0.f;
#pragma unroll
            for (int c4 = 0; c4 < 16; ++c4) {
                float4 e = er[c4], xv = xr[c4];
                dot += e.x * xv.x + e.y * xv.y + e.z * xv.z + e.w * xv.w;
            }
            float d = ens[k] - 2.f * dot;            // exact fp32
            if (d < dm) { dm = d; im = k; }
        }
#pragma unroll
        for (int off = 1; off < 64; off <<= 1) {
            float od = __shfl_xor(dm, off, 64);
            int   oi = __shfl_xor(im, off, 64);
            if (od < dm || (od == dm && oi < im)) { dm = od; im = oi; }
        }
        if (lane == 0) { wdd[w] = dm; wii[w] = im; }
        __syncthreads();
        if (tid == 0) {
            float bd = wdd[0]; int bi = wii[0];
#pragma unroll
            for (int ww = 1; ww < 8; ++ww)
                if (wdd[ww] < bd || (wdd[ww] == bd && wii[ww] < bi)) { bd = wdd[ww]; bi = wii[ww]; }
            rd1[q] = bd; ri[q] = bi;                 // final exact result
        }
        __syncthreads();
    }

    // ---- per-block LDS histogram -> coalesced u16x2 row write; SSE partial ----
    lhist[tid] = 0u; lhist[512 + tid] = 0u;          // zero 1024 bins (512 thr)
    __syncthreads();
    if (tid < QT) atomicAdd(&lhist[ri[tid]], 1u);    // LDS atomics: ~free
    if (tid < QT) {
        float sp = rd1[tid] + xnorm[tid];            // ||q-x||^2 (exact for rescued)
#pragma unroll
        for (int off = 32; off; off >>= 1) sp += __shfl_down(sp, off, 64);
        if (lane == 0) spw[tid >> 6] = sp;
    }
    __syncthreads();
    hbuf[blockIdx.x * 512 + tid] = lhist[2 * tid] | (lhist[2 * tid + 1] << 16);
    if (tid == 0) partials[blockIdx.x] = spw[0] + spw[1] + spw[2] + spw[3];

    // ---- fused output write: four 64-query quarters through the LDS tile ----
#pragma unroll
    for (int h = 0; h < 4; ++h) {
        {   // gather from frag-layout table: thread = (q = tid>>3, j8 = tid&7)
            int q = tid >> 3, j8 = tid & 7;          // 8 dims per thread
            int code = ri[h * 64 + q];
            int ct = code >> 4, cl = code & 15;
            int kc = j8 >> 2, qd = j8 & 3;
            const short* tb = btab + ct * 2048 + kc * 1024;
            short8 hi = *(const short8*)&tb[(qd * 16 + cl) * 8];
            short8 lo = *(const short8*)&tb[512 + (qd * 16 + cl) * 8];
            float* dst = &tile[q * 72 + j8 * 8];
#pragma unroll
            for (int k = 0; k < 8; ++k)
                dst[k] = bf2f((unsigned short)hi[k]) + bf2f((unsigned short)lo[k]);
        }
        __syncthreads();
        {   // transposed coalesced write
            int c = tid >> 3;
            float* ob = out + b * (CDIM * HW_SZ) + c * HW_SZ + hw0 + h * 64;
#pragma unroll
            for (int p = 0; p < 2; ++p) {
                int q = ((tid & 7) + p * 8) * 4;   // 0..60
                float4 v;
                v.x = tile[(q + 0) * 72 + c];
                v.y = tile[(q + 1) * 72 + c];
                v.z = tile[(q + 2) * 72 + c];
                v.w = tile[(q + 3) * 72 + c];
                *(float4*)&ob[q] = v;
            }
        }
        if (h < 3) __syncthreads();
    }
}

// --------------------------------------------------------------- k_final ----
// 1 block x 1024 thr. Sums 256 per-block u16x2 histogram rows (row-coalesced,
// 512 KB from L2, 2-way row-split across thread halves), then entropy + loss.
__global__ __launch_bounds__(1024, 1)
void k_final(const unsigned int* __restrict__ hbuf,
             const float* __restrict__ partials, float* __restrict__ out) {
    __shared__ unsigned int hc[2][512][2];   // [half][word][lo/hi]  8 KB
    __shared__ float fin[32];
    const int tid  = threadIdx.x;            // 0..1023
    const int tlo  = tid & 511;
    const int half = tid >> 9;

    unsigned c0 = 0, c1 = 0;
#pragma unroll 8
    for (int r = 0; r < NBLK / 2; ++r) {     // 128 rows per half
        unsigned v = hbuf[(half * (NBLK / 2) + r) * 512 + tlo];
        c0 += v & 0xffffu;
        c1 += v >> 16;
    }
    hc[half][tlo][0] = c0;
    hc[half][tlo][1] = c1;
    __syncthreads();

    float s = 0.f, ss = 0.f;
    if (half == 0) {
        float p0 = (float)(hc[0][tlo][0] + hc[1][tlo][0]) * (1.0f / 65536.0f);
        float p1 = (float)(hc[0][tlo][1] + hc[1][tlo][1]) * (1.0f / 65536.0f);
        s = p0 * logf(p0 + 1e-10f) + p1 * logf(p1 + 1e-10f);
        if (tlo < NBLK) ss = partials[tlo];
    }
#pragma unroll
    for (int off = 32; off; off >>= 1) {
        ss += __shfl_down(ss, off, 64);
        s  += __shfl_down(s, off, 64);
    }
    const int w = tid >> 6;
    if ((tid & 63) == 0) { fin[w] = ss; fin[16 + w] = s; }
    __syncthreads();
    if (tid == 0) {
        float sse = 0.f, ent = 0.f;
#pragma unroll
        for (int i = 0; i < 16; ++i) { sse += fin[i]; ent += fin[16 + i]; }
        out[OUT_ELEMS]     = 1.25f * sse * (1.0f / (float)OUT_ELEMS);  // loss
        out[OUT_ELEMS + 1] = expf(-ent);                                // perplexity
    }
}

// ---------------------------------------------------------------- launch ----
extern "C" void kernel_launch(void* const* d_in, const int* in_sizes, int n_in,
                              void* d_out, int out_size, void* d_ws, size_t ws_size,
                              hipStream_t stream) {
    const float* x   = (const float*)d_in[0];
    const float* emb = (const float*)d_in[1];
    float* out = (float*)d_out;
    char* ws = (char*)d_ws;
    float*        enorm    = (float*)(ws);
    float*        partials = (float*)(ws + 8192);
    short*        btab     = (short*)(ws + 12288);
    unsigned int* hbuf     = (unsigned int*)(ws + 274432);

    k_prep  <<<64, 256, 0, stream>>>(emb, enorm, btab);
    k_argmin<<<NBLK, 512, 0, stream>>>(x, emb, btab, enorm, hbuf, partials, out);
    k_final <<<1, 1024, 0, stream>>>(hbuf, partials, out);
}